// Round 2
// baseline (393.037 us; speedup 1.0000x reference)
//
#include <hip/hip_runtime.h>

// DistillingLoss: mean over batch of sum_j(-target_ij * log(input_ij))
// B=8192, C=32000, fp32 in, scalar fp32 out.
// Memory-bound streaming reduction: 2.097 GB read -> ~333 us at 6.3 TB/s.
//
// R1: 32-bit indexing (byte offsets < 2^31), exact trip count (125 iters per
// thread), manual unroll x5 (10 loads in flight/wave), log2-domain
// accumulation (defer ln2 scale to the block partial), 4 accumulators,
// nontemporal loads (pure streaming, no reuse).

#define DL_BATCH 8192
#define DL_CLASSES 32000

typedef float f4 __attribute__((ext_vector_type(4)));

#define DL_GRID 2048
#define DL_BLOCK 256
// n4 = 8192*32000/4 = 65,536,000 = (2048*256) * 125 exactly.
#define DL_ITERS_TOTAL 125
#define DL_UNROLL 5
#define DL_OUTER (DL_ITERS_TOTAL / DL_UNROLL)  // 25

__global__ __launch_bounds__(DL_BLOCK) void dl_partial_kernel(
    const f4* __restrict__ inp,
    const f4* __restrict__ tgt,
    float* __restrict__ partials)
{
    const unsigned stride = DL_GRID * DL_BLOCK;             // 524288
    const unsigned idx = blockIdx.x * DL_BLOCK + threadIdx.x;

    float a0 = 0.0f, a1 = 0.0f, a2 = 0.0f, a3 = 0.0f;

    for (int it = 0; it < DL_OUTER; ++it) {
        const unsigned base = idx + (unsigned)it * (DL_UNROLL * stride);
        f4 x[DL_UNROLL], t[DL_UNROLL];
        #pragma unroll
        for (int u = 0; u < DL_UNROLL; ++u) {
            x[u] = __builtin_nontemporal_load(&inp[base + u * stride]);
            t[u] = __builtin_nontemporal_load(&tgt[base + u * stride]);
        }
        #pragma unroll
        for (int u = 0; u < DL_UNROLL; ++u) {
            // accumulate -t * log2(x); scale by ln2 once per block.
            a0 = fmaf(-t[u].x, __log2f(x[u].x), a0);
            a1 = fmaf(-t[u].y, __log2f(x[u].y), a1);
            a2 = fmaf(-t[u].z, __log2f(x[u].z), a2);
            a3 = fmaf(-t[u].w, __log2f(x[u].w), a3);
        }
    }

    float acc = (a0 + a1) + (a2 + a3);

    // wave-64 reduce
    #pragma unroll
    for (int off = 32; off > 0; off >>= 1)
        acc += __shfl_down(acc, off, 64);

    __shared__ float wave_sums[4];  // 256 threads = 4 waves
    const int wave = threadIdx.x >> 6;
    const int lane = threadIdx.x & 63;
    if (lane == 0) wave_sums[wave] = acc;
    __syncthreads();

    if (threadIdx.x == 0) {
        // fold the log2 -> ln conversion in here (one mul per block)
        partials[blockIdx.x] =
            (wave_sums[0] + wave_sums[1] + wave_sums[2] + wave_sums[3])
            * 0.6931471805599453f;
    }
}

// Pass 2: single block, double accumulation of block partials, / BATCH.
// Deterministic (no float atomics).
__global__ __launch_bounds__(256) void dl_final_kernel(
    const float* __restrict__ partials,
    int n,
    float* __restrict__ out)
{
    double acc = 0.0;
    for (int i = threadIdx.x; i < n; i += blockDim.x)
        acc += (double)partials[i];

    #pragma unroll
    for (int off = 32; off > 0; off >>= 1)
        acc += __shfl_down(acc, off, 64);

    __shared__ double wave_sums[4];
    const int wave = threadIdx.x >> 6;
    const int lane = threadIdx.x & 63;
    if (lane == 0) wave_sums[wave] = acc;
    __syncthreads();

    if (threadIdx.x == 0) {
        double total = wave_sums[0] + wave_sums[1] + wave_sums[2] + wave_sums[3];
        out[0] = (float)(total / (double)DL_BATCH);
    }
}

extern "C" void kernel_launch(void* const* d_in, const int* in_sizes, int n_in,
                              void* d_out, int out_size, void* d_ws, size_t ws_size,
                              hipStream_t stream) {
    const f4* inp = (const f4*)d_in[0];
    const f4* tgt = (const f4*)d_in[1];
    float* out = (float*)d_out;
    float* partials = (float*)d_ws;

    dl_partial_kernel<<<DL_GRID, DL_BLOCK, 0, stream>>>(inp, tgt, partials);
    dl_final_kernel<<<1, 256, 0, stream>>>(partials, DL_GRID, out);
}

// Round 3
// 366.185 us; speedup vs baseline: 1.0733x; 1.0733x over previous
//
#include <hip/hip_runtime.h>

// DistillingLoss: mean over batch of sum_j(-target_ij * log(input_ij))
// B=8192, C=32000, fp32 in, scalar fp32 out.
// Memory-bound streaming reduction: 2.097 GB read -> ~333 us at 6.3 TB/s.
//
// R2: R0 structure + forced max occupancy (__launch_bounds__(256,8) keeps
// VGPR <= 64, 8 waves/SIMD), 32-bit indexing, log2-domain accumulation,
// unroll x2 (4 loads in flight/wave), NO nontemporal (R1 showed it hurts).
// Grid 2000 -> exactly 128 iters/thread, no tail.

#define DL_BATCH 8192
#define DL_CLASSES 32000

typedef float f4 __attribute__((ext_vector_type(4)));

#define DL_GRID 2000
#define DL_BLOCK 256
// n4 = 8192*32000/4 = 65,536,000 = (2000*256) * 128 exactly.
#define DL_OUTER 64   // 128 iters, unrolled x2

__global__ __launch_bounds__(DL_BLOCK, 8) void dl_partial_kernel(
    const f4* __restrict__ inp,
    const f4* __restrict__ tgt,
    float* __restrict__ partials)
{
    const unsigned stride = DL_GRID * DL_BLOCK;             // 512000
    const unsigned idx = blockIdx.x * DL_BLOCK + threadIdx.x;

    float a0 = 0.0f, a1 = 0.0f, a2 = 0.0f, a3 = 0.0f;

    #pragma unroll 1
    for (int it = 0; it < DL_OUTER; ++it) {
        const unsigned base = idx + (unsigned)it * (2u * stride);
        f4 x0 = inp[base];
        f4 t0 = tgt[base];
        f4 x1 = inp[base + stride];
        f4 t1 = tgt[base + stride];

        // accumulate -t * log2(x); scale by ln2 once per block.
        a0 = fmaf(-t0.x, __log2f(x0.x), a0);
        a1 = fmaf(-t0.y, __log2f(x0.y), a1);
        a2 = fmaf(-t0.z, __log2f(x0.z), a2);
        a3 = fmaf(-t0.w, __log2f(x0.w), a3);
        a0 = fmaf(-t1.x, __log2f(x1.x), a0);
        a1 = fmaf(-t1.y, __log2f(x1.y), a1);
        a2 = fmaf(-t1.z, __log2f(x1.z), a2);
        a3 = fmaf(-t1.w, __log2f(x1.w), a3);
    }

    float acc = (a0 + a1) + (a2 + a3);

    // wave-64 reduce
    #pragma unroll
    for (int off = 32; off > 0; off >>= 1)
        acc += __shfl_down(acc, off, 64);

    __shared__ float wave_sums[4];  // 256 threads = 4 waves
    const int wave = threadIdx.x >> 6;
    const int lane = threadIdx.x & 63;
    if (lane == 0) wave_sums[wave] = acc;
    __syncthreads();

    if (threadIdx.x == 0) {
        // fold the log2 -> ln conversion in here (one mul per block)
        partials[blockIdx.x] =
            (wave_sums[0] + wave_sums[1] + wave_sums[2] + wave_sums[3])
            * 0.6931471805599453f;
    }
}

// Pass 2: single block, double accumulation of block partials, / BATCH.
// Deterministic (no float atomics).
__global__ __launch_bounds__(256) void dl_final_kernel(
    const float* __restrict__ partials,
    int n,
    float* __restrict__ out)
{
    double acc = 0.0;
    for (int i = threadIdx.x; i < n; i += blockDim.x)
        acc += (double)partials[i];

    #pragma unroll
    for (int off = 32; off > 0; off >>= 1)
        acc += __shfl_down(acc, off, 64);

    __shared__ double wave_sums[4];
    const int wave = threadIdx.x >> 6;
    const int lane = threadIdx.x & 63;
    if (lane == 0) wave_sums[wave] = acc;
    __syncthreads();

    if (threadIdx.x == 0) {
        double total = wave_sums[0] + wave_sums[1] + wave_sums[2] + wave_sums[3];
        out[0] = (float)(total / (double)DL_BATCH);
    }
}

extern "C" void kernel_launch(void* const* d_in, const int* in_sizes, int n_in,
                              void* d_out, int out_size, void* d_ws, size_t ws_size,
                              hipStream_t stream) {
    const f4* inp = (const f4*)d_in[0];
    const f4* tgt = (const f4*)d_in[1];
    float* out = (float*)d_out;
    float* partials = (float*)d_ws;

    dl_partial_kernel<<<DL_GRID, DL_BLOCK, 0, stream>>>(inp, tgt, partials);
    dl_final_kernel<<<1, 256, 0, stream>>>(partials, DL_GRID, out);
}

// Round 4
// 363.783 us; speedup vs baseline: 1.0804x; 1.0066x over previous
//
#include <hip/hip_runtime.h>

// DistillingLoss: mean over batch of sum_j(-target_ij * log(input_ij))
// B=8192, C=32000, fp32 in, scalar fp32 out.
// Memory-bound streaming reduction: 2.097 GB read -> ~333 us at 6.3 TB/s.
//
// R3: float8 per stream per step (2 adjacent global_load_dwordx4 off one
// address reg), unroll x2 -> 8 loads in flight per wave, 2 KB contiguous
// per wave per stream-step. launch_bounds(256,8) keeps VGPR <= 64 for
// 8 waves/SIMD. Grid 2000 -> exactly 64 f8-steps/thread, no tail.
// 32-bit indexing (max byte offset ~1.05e9 < 2^31), log2-domain accum.

#define DL_BATCH 8192
#define DL_CLASSES 32000

typedef float f4 __attribute__((ext_vector_type(4)));
typedef float f8 __attribute__((ext_vector_type(8)));

#define DL_GRID 2000
#define DL_BLOCK 256
// n8 = 8192*32000/8 = 32,768,000 = (2000*256) * 64 exactly.
#define DL_OUTER 32   // 64 f8-steps, unrolled x2

__global__ __launch_bounds__(DL_BLOCK, 8) void dl_partial_kernel(
    const f8* __restrict__ inp,
    const f8* __restrict__ tgt,
    float* __restrict__ partials)
{
    const unsigned stride = DL_GRID * DL_BLOCK;             // 512000 f8 units
    const unsigned idx = blockIdx.x * DL_BLOCK + threadIdx.x;

    float a0 = 0.0f, a1 = 0.0f, a2 = 0.0f, a3 = 0.0f;

    #pragma unroll 1
    for (int it = 0; it < DL_OUTER; ++it) {
        const unsigned base = idx + (unsigned)it * (2u * stride);
        f8 x0 = inp[base];
        f8 t0 = tgt[base];
        f8 x1 = inp[base + stride];
        f8 t1 = tgt[base + stride];

        // accumulate -t * log2(x); scale by ln2 once per block.
        #pragma unroll
        for (int j = 0; j < 8; j += 4) {
            a0 = fmaf(-t0[j + 0], __log2f(x0[j + 0]), a0);
            a1 = fmaf(-t0[j + 1], __log2f(x0[j + 1]), a1);
            a2 = fmaf(-t0[j + 2], __log2f(x0[j + 2]), a2);
            a3 = fmaf(-t0[j + 3], __log2f(x0[j + 3]), a3);
            a0 = fmaf(-t1[j + 0], __log2f(x1[j + 0]), a0);
            a1 = fmaf(-t1[j + 1], __log2f(x1[j + 1]), a1);
            a2 = fmaf(-t1[j + 2], __log2f(x1[j + 2]), a2);
            a3 = fmaf(-t1[j + 3], __log2f(x1[j + 3]), a3);
        }
    }

    float acc = (a0 + a1) + (a2 + a3);

    // wave-64 reduce
    #pragma unroll
    for (int off = 32; off > 0; off >>= 1)
        acc += __shfl_down(acc, off, 64);

    __shared__ float wave_sums[4];  // 256 threads = 4 waves
    const int wave = threadIdx.x >> 6;
    const int lane = threadIdx.x & 63;
    if (lane == 0) wave_sums[wave] = acc;
    __syncthreads();

    if (threadIdx.x == 0) {
        // fold the log2 -> ln conversion in here (one mul per block)
        partials[blockIdx.x] =
            (wave_sums[0] + wave_sums[1] + wave_sums[2] + wave_sums[3])
            * 0.6931471805599453f;
    }
}

// Pass 2: single block, double accumulation of block partials, / BATCH.
// Deterministic (no float atomics).
__global__ __launch_bounds__(256) void dl_final_kernel(
    const float* __restrict__ partials,
    int n,
    float* __restrict__ out)
{
    double acc = 0.0;
    for (int i = threadIdx.x; i < n; i += blockDim.x)
        acc += (double)partials[i];

    #pragma unroll
    for (int off = 32; off > 0; off >>= 1)
        acc += __shfl_down(acc, off, 64);

    __shared__ double wave_sums[4];
    const int wave = threadIdx.x >> 6;
    const int lane = threadIdx.x & 63;
    if (lane == 0) wave_sums[wave] = acc;
    __syncthreads();

    if (threadIdx.x == 0) {
        double total = wave_sums[0] + wave_sums[1] + wave_sums[2] + wave_sums[3];
        out[0] = (float)(total / (double)DL_BATCH);
    }
}

extern "C" void kernel_launch(void* const* d_in, const int* in_sizes, int n_in,
                              void* d_out, int out_size, void* d_ws, size_t ws_size,
                              hipStream_t stream) {
    const f8* inp = (const f8*)d_in[0];
    const f8* tgt = (const f8*)d_in[1];
    float* out = (float*)d_out;
    float* partials = (float*)d_ws;

    dl_partial_kernel<<<DL_GRID, DL_BLOCK, 0, stream>>>(inp, tgt, partials);
    dl_final_kernel<<<1, 256, 0, stream>>>(partials, DL_GRID, out);
}